// Round 2
// baseline (152.389 us; speedup 1.0000x reference)
//
#include <hip/hip_runtime.h>
#include <hip/hip_bf16.h>
#include <cmath>
#include <complex>

// Problem constants
constexpr int TT  = 50;            // time length
constexpr int NB  = 50;            // batch
constexpr int NC  = 4096;          // channels
constexpr int NCH = NB * NC;       // 204800 independent series
constexpr int PAD = 49;
constexpr int EXT = TT + 2 * PAD;  // 148
constexpr int CT  = 16;            // channel tile per block (block = CT x NB threads)

struct Coefs {
    double b0[2][2], b1[2][2], b2[2][2], a1[2][2], a2[2][2];
    double zi0[2][2], zi1[2][2];
};

// ---------------- Setup kernel: build the 50x50 filtfilt+demean matrix per band ----
// Mt[(band*TT + k)*TT + t] = d y[t] / d x[k]  (y demeaned over t), double precision.
// One block per band, thread j = basis column. State array lives in LDS (column j
// is private to thread j, no syncs needed) to avoid a 296-VGPR scratch spill.
__global__ void __launch_bounds__(64) build_M(float* __restrict__ Mt, Coefs cf) {
    __shared__ double e[EXT][TT];   // 148*50*8 = 59.2 KB
    const int band = blockIdx.x;
    const int j = threadIdx.x;
    if (j >= TT) return;

    // odd extension of basis vector e_j
#pragma unroll
    for (int i = 0; i < PAD; ++i)
        e[i][j] = 2.0 * (j == 0 ? 1.0 : 0.0) - ((PAD - i) == j ? 1.0 : 0.0);
#pragma unroll
    for (int t = 0; t < TT; ++t) e[PAD + t][j] = (t == j) ? 1.0 : 0.0;
#pragma unroll
    for (int i = 0; i < PAD; ++i)
        e[PAD + TT + i][j] = 2.0 * (j == TT - 1 ? 1.0 : 0.0) - ((TT - 2 - i) == j ? 1.0 : 0.0);

    const double x0 = e[0][j];
#pragma unroll
    for (int s = 0; s < 2; ++s) {
        const double b0 = cf.b0[band][s], b1 = cf.b1[band][s], b2 = cf.b2[band][s];
        const double a1 = cf.a1[band][s], a2 = cf.a2[band][s];
        double z0 = cf.zi0[band][s] * x0, z1 = cf.zi1[band][s] * x0;
#pragma unroll
        for (int i = 0; i < EXT; ++i) {
            const double xt = e[i][j];
            const double yt = b0 * xt + z0;
            z0 = b1 * xt + z1 - a1 * yt;
            z1 = b2 * xt - a2 * yt;
            e[i][j] = yt;
        }
    }
    const double y0 = e[EXT - 1][j];
#pragma unroll
    for (int s = 0; s < 2; ++s) {
        const double b0 = cf.b0[band][s], b1 = cf.b1[band][s], b2 = cf.b2[band][s];
        const double a1 = cf.a1[band][s], a2 = cf.a2[band][s];
        double z0 = cf.zi0[band][s] * y0, z1 = cf.zi1[band][s] * y0;
#pragma unroll
        for (int m = 0; m < EXT; ++m) {
            const int i = EXT - 1 - m;
            const double xt = e[i][j];
            const double yt = b0 * xt + z0;
            z0 = b1 * xt + z1 - a1 * yt;
            z1 = b2 * xt - a2 * yt;
            e[i][j] = yt;
        }
    }
    // slice [PAD, PAD+TT) and fold the demean over t
    double mean = 0.0;
#pragma unroll
    for (int t = 0; t < TT; ++t) mean += e[PAD + t][j];
    mean *= (1.0 / TT);
#pragma unroll
    for (int t = 0; t < TT; ++t)
        Mt[(band * TT + j) * TT + t] = (float)(e[PAD + t][j] - mean);
}

// ---------------- Main kernel -------------------------------------------------------
// Block = (CT channels) x (all 50 batches). Thread (c,b) computes y[.,b,c] = M x[.,b,c]
// in registers, publishes its (mean, 1/std) to LDS, then applies the REFERENCE'S
// BROADCASTING QUIRK: out[t,b,c] = (y[t,b,c] - mu[t,c]) * invs[t,c]  -- stats indexed
// by the TIME position t (batch row t), not by b. That quirk is why ref absmax ~ 2960.
__global__ void __launch_bounds__(CT * NB, 1)
filt_main(const float* __restrict__ x, const float* __restrict__ Mt,
          float* __restrict__ out) {
    const int tx = threadIdx.x;                 // channel within tile
    const int b  = threadIdx.y;                 // batch
    const int c  = blockIdx.x * CT + tx;
    const int i  = b * NC + c;                  // channel index into [B,C] plane

    __shared__ float sm_mu[NB][CT];
    __shared__ float sm_inv[NB][CT];

    for (int band = 0; band < 2; ++band) {
        float f[TT];
#pragma unroll
        for (int t = 0; t < TT; ++t) f[t] = 0.f;

        for (int k = 0; k < TT; ++k) {
            const float xk = x[(size_t)k * NCH + i];                  // coalesced
            const float* __restrict__ r = Mt + (band * TT + k) * TT;  // uniform -> s_load
#pragma unroll
            for (int t = 0; t < TT; ++t) f[t] = fmaf(r[t], xk, f[t]);
        }

        // per-(b,c) stats (ddof=1 std about the actual mean, matching np.std)
        float mu = 0.f;
#pragma unroll
        for (int t = 0; t < TT; ++t) mu += f[t];
        mu *= (1.0f / TT);
        float ss = 0.f;
#pragma unroll
        for (int t = 0; t < TT; ++t) {
            const float h = f[t] - mu;
            ss = fmaf(h, h, ss);
        }
        const float inv = 1.0f / sqrtf(ss * (1.0f / (TT - 1)));
        sm_mu[b][tx] = mu;
        sm_inv[b][tx] = inv;
        __syncthreads();

#pragma unroll
        for (int t = 0; t < TT; ++t) {
            const float v = (f[t] - sm_mu[t][tx]) * sm_inv[t][tx];   // QUIRK: [t], not [b]
            out[(size_t)(band * TT + t) * NCH + i] = v;
        }
        __syncthreads();   // protect LDS stats before next band overwrites
    }
}

// ---------------- Host: Butterworth bandpass SOS + zi (reference-exact, double) ----
static Coefs make_coefs() {
    Coefs cf;
    const double bands[2][2] = {{0.05, 0.15}, {0.2, 0.4}};
    const int n = 2;  // ORDER
    for (int bd = 0; bd < 2; ++bd) {
        const double fs = 2.0;
        const double w1 = bands[bd][0], w2 = bands[bd][1];
        const double warped0 = 2.0 * fs * std::tan(M_PI * w1 / fs);
        const double warped1 = 2.0 * fs * std::tan(M_PI * w2 / fs);
        const double bw = warped1 - warped0;
        const double wo = std::sqrt(warped0 * warped1);
        std::complex<double> p_bp[4];
        for (int k = 1; k <= n; ++k) {
            std::complex<double> p = -std::exp(std::complex<double>(0.0, M_PI * (2 * k - 1) / (2.0 * n)));
            std::complex<double> plp = p * (bw / 2.0);
            std::complex<double> disc = std::sqrt(plp * plp - std::complex<double>(wo * wo, 0.0));
            p_bp[k - 1] = plp + disc;
            p_bp[n + k - 1] = plp - disc;
        }
        const double fs2 = 2.0 * fs;
        std::complex<double> prod(1.0, 0.0);
        for (int i = 0; i < 2 * n; ++i) prod *= (fs2 - p_bp[i]);
        const double gain = std::pow(bw, n) * std::pow(fs2, n) / prod.real();
        std::complex<double> p_d[4];
        for (int i = 0; i < 2 * n; ++i) p_d[i] = (fs2 + p_bp[i]) / (fs2 - p_bp[i]);
        double sos[2][6];
        int cnt = 0;
        for (int i = 0; i < 2 * n; ++i) {
            if (p_d[i].imag() > 0) {
                const double g = (cnt == 0) ? gain : 1.0;
                sos[cnt][0] = g;
                sos[cnt][1] = 0.0;
                sos[cnt][2] = -g;
                sos[cnt][3] = 1.0;
                sos[cnt][4] = -2.0 * p_d[i].real();
                sos[cnt][5] = std::norm(p_d[i]);
                ++cnt;
            }
        }
        double scale = 1.0;
        for (int s = 0; s < 2; ++s) {
            const double b0 = sos[s][0], b1 = sos[s][1], b2 = sos[s][2];
            const double a1 = sos[s][4], a2 = sos[s][5];
            const double B0 = b1 - a1 * b0, B1 = b2 - a2 * b0;
            const double det = 1.0 + a1 + a2;
            cf.b0[bd][s] = b0; cf.b1[bd][s] = b1; cf.b2[bd][s] = b2;
            cf.a1[bd][s] = a1; cf.a2[bd][s] = a2;
            cf.zi0[bd][s] = scale * (B0 + B1) / det;
            cf.zi1[bd][s] = scale * ((1.0 + a1) * B1 - a2 * B0) / det;
            scale *= (b0 + b1 + b2) / (1.0 + a1 + a2);
        }
    }
    return cf;
}

extern "C" void kernel_launch(void* const* d_in, const int* in_sizes, int n_in,
                              void* d_out, int out_size, void* d_ws, size_t ws_size,
                              hipStream_t stream) {
    const float* x = (const float*)d_in[0];
    float* out = (float*)d_out;
    float* Mt = (float*)d_ws;  // 2*50*50 floats = 20 KB

    const Coefs cf = make_coefs();
    build_M<<<dim3(2), dim3(64), 0, stream>>>(Mt, cf);
    filt_main<<<dim3(NC / CT), dim3(CT, NB), 0, stream>>>(x, Mt, out);
}